// Round 6
// baseline (2136.406 us; speedup 1.0000x reference)
//
#include <hip/hip_runtime.h>
#include <cfloat>

// Problem constants: B=16, N=8192, C=256; M derived from out_size (=2048).
#define BB 16
#define NN 8192
#define CC 256
#define NT 512                  // threads per FPS block (8 waves)
#define PPT 16                  // points per thread (= one spatial cluster)
#define NPAIR (PPT / 2)         // 8 packed f32x2 pairs
#define NWAVES (NT / 64)        // 8
#define TBLOCKS 240             // transpose helper blocks (fill idle CUs)
#define NTILES (BB * (CC / 64) * (NN / 64))   // 16*4*128 = 8192 64x64 tiles
#define NBUCK 4096              // 12-bit morton buckets

typedef float    v2f __attribute__((ext_vector_type(2)));
typedef unsigned v2u __attribute__((ext_vector_type(2)));
typedef unsigned uu;
typedef unsigned long long ull;

// lgkm-only barrier (R5): our only cross-wave data is LDS; skip vmcnt drain.
#define LDS_BARRIER() __asm__ __volatile__("s_waitcnt lgkmcnt(0)\n\ts_barrier" ::: "memory")

// FPS LDS view: SORTED coords + orig indices + histogram + reduce slots.
// ~131 KB static -> 1 block/CU (current 98.8 KB already works; HW limit 160K).
struct SmemFPS {
  float px[NN], py[NN], pz[NN];           // 96 KB sorted coord mirror
  unsigned short pn[NN];                  // 16 KB sorted original indices
  int   hist[NBUCK];                      // 16 KB histogram -> offsets
  ull   key[2][NWAVES];                   // double-buffered wave keys
  float red[NWAVES][9];                   // sum/min/max xyz wave partials
  float st9[9];                           // ctr xyz, mn xyz, mx xyz
  int   wsum[NWAVES];
};
struct SmemT { float tile[64][65]; };     // padded transpose tile
union Smem { SmemFPS f; SmemT t; };

// ---- guaranteed-packed f32 math (VOP3P); per-half plain IEEE RN ops ----
__device__ __forceinline__ v2f pk_sub(v2f a, v2f b) {
  v2f d;
  asm("v_pk_add_f32 %0, %1, %2 neg_lo:[0,1] neg_hi:[0,1]"
      : "=v"(d) : "v"(a), "v"(b));
  return d;
}
__device__ __forceinline__ v2f pk_mul(v2f a, v2f b) {
  v2f d;
  asm("v_pk_mul_f32 %0, %1, %2" : "=v"(d) : "v"(a), "v"(b));
  return d;
}
__device__ __forceinline__ v2f pk_add(v2f a, v2f b) {
  v2f d;
  asm("v_pk_add_f32 %0, %1, %2" : "=v"(d) : "v"(a), "v"(b));
  return d;
}

__device__ __forceinline__ uu umin2(uu a, uu b) { return a < b ? a : b; }
__device__ __forceinline__ uu umax2(uu a, uu b) { return a > b ? a : b; }
__device__ __forceinline__ ull max64(ull a, ull b) { return a > b ? a : b; }

// key = (dist_bits << 32) | ~((orig_n << 13) | sorted_pos).
// dist >= 0 -> u32 bit order == f32 order. Max key = max dist; tie -> larger
// low word = smaller orig_n (numpy first-occurrence). sorted_pos rides along
// (n is unique, so it never decides) to address the sorted coord arrays.
template <int CTRL>
__device__ __forceinline__ ull dpp_max64(ull x) {
  int lo = (int)(uu)x;
  int hi = (int)(uu)(x >> 32);
  int plo = __builtin_amdgcn_update_dpp(0, lo, CTRL, 0xF, 0xF, true);
  int phi = __builtin_amdgcn_update_dpp(0, hi, CTRL, 0xF, 0xF, true);
  ull p = ((ull)(uu)phi << 32) | (uu)plo;
  return max64(x, p);
}

// Wave64 max funneled into lane 63, all on the VALU pipe.
__device__ __forceinline__ ull wave_max63(ull k) {
  k = dpp_max64<0xB1>(k);    // quad_perm xor1
  k = dpp_max64<0x4E>(k);    // quad_perm xor2
  k = dpp_max64<0x124>(k);   // row_ror:4
  k = dpp_max64<0x128>(k);   // row_ror:8 -> full 16-lane row max
  k = dpp_max64<0x142>(k);   // row_bcast15
  k = dpp_max64<0x143>(k);   // row_bcast31 -> lane 63 has wave max
  return k;
}

__device__ __forceinline__ int morton12(int x, int y, int z) {
  int c = 0;
#pragma unroll
  for (int i = 0; i < 4; ++i) {
    c |= ((x >> i) & 1) << (3 * i);
    c |= ((y >> i) & 1) << (3 * i + 1);
    c |= ((z >> i) & 1) << (3 * i + 2);
  }
  return c;
}

__global__ __launch_bounds__(NT)
void fps_fused_kernel(const float* __restrict__ pts,
                      const float* __restrict__ feats,
                      float* __restrict__ out_pts,
                      int* __restrict__ idx_out,
                      float* __restrict__ trans, int M, int do_trans) {
  __shared__ Smem sm;
  const int t = threadIdx.x;

  if (blockIdx.x >= BB) {
    // ---------------- transpose path (unchanged) ----------------
    if (!do_trans) return;
    for (int tileId = blockIdx.x - BB; tileId < NTILES; tileId += TBLOCKS) {
      int b  = tileId / ((CC / 64) * (NN / 64));
      int r  = tileId % ((CC / 64) * (NN / 64));
      int ct = r / (NN / 64);
      int nt = r % (NN / 64);
      const float* src = feats + ((size_t)b * CC + ct * 64) * NN + nt * 64;
      float* dst = trans + ((size_t)b * NN + nt * 64) * CC + ct * 64;
#pragma unroll
      for (int i = 0; i < 2; ++i) {
        int f = t + i * NT;
        int c = f >> 4, n4 = f & 15;
        float4 v = *(const float4*)(src + (size_t)c * NN + n4 * 4);
        sm.t.tile[c][n4 * 4 + 0] = v.x;
        sm.t.tile[c][n4 * 4 + 1] = v.y;
        sm.t.tile[c][n4 * 4 + 2] = v.z;
        sm.t.tile[c][n4 * 4 + 3] = v.w;
      }
      __syncthreads();
#pragma unroll
      for (int i = 0; i < 2; ++i) {
        int f = t + i * NT;
        int n = f >> 4, c4 = f & 15;
        float4 o;
        o.x = sm.t.tile[c4 * 4 + 0][n];
        o.y = sm.t.tile[c4 * 4 + 1][n];
        o.z = sm.t.tile[c4 * 4 + 2][n];
        o.w = sm.t.tile[c4 * 4 + 3][n];
        *(float4*)(dst + (size_t)n * CC + c4 * 4) = o;
      }
      __syncthreads();
    }
    return;
  }

  // ---------------- FPS path ----------------
  const int b = blockIdx.x;
  const int wave = t >> 6;
  const int lane = t & 63;
  const float* base = pts + (size_t)b * 3 * NN;

  // ---- phase 0: raw coalesced load + block stats (sum/min/max per axis) ----
  float rx[PPT], ry[PPT], rz[PPT];
#pragma unroll
  for (int k = 0; k < PPT; ++k) {
    int n = t + k * NT;
    rx[k] = base[n]; ry[k] = base[NN + n]; rz[k] = base[2 * NN + n];
  }
  // centroid sums in EXACT same order as R5 (k ascending) -> bit-same centroid
  float sx = 0.f, sy = 0.f, sz = 0.f;
  float mnx = rx[0], mny = ry[0], mnz = rz[0];
  float mxx = rx[0], mxy = ry[0], mxz = rz[0];
#pragma unroll
  for (int k = 0; k < PPT; ++k) {
    sx += rx[k]; sy += ry[k]; sz += rz[k];
    mnx = fminf(mnx, rx[k]); mny = fminf(mny, ry[k]); mnz = fminf(mnz, rz[k]);
    mxx = fmaxf(mxx, rx[k]); mxy = fmaxf(mxy, ry[k]); mxz = fmaxf(mxz, rz[k]);
  }
#pragma unroll
  for (int off = 32; off > 0; off >>= 1) {
    sx += __shfl_xor(sx, off); sy += __shfl_xor(sy, off); sz += __shfl_xor(sz, off);
    mnx = fminf(mnx, __shfl_xor(mnx, off));
    mny = fminf(mny, __shfl_xor(mny, off));
    mnz = fminf(mnz, __shfl_xor(mnz, off));
    mxx = fmaxf(mxx, __shfl_xor(mxx, off));
    mxy = fmaxf(mxy, __shfl_xor(mxy, off));
    mxz = fmaxf(mxz, __shfl_xor(mxz, off));
  }
  if (lane == 0) {
    sm.f.red[wave][0] = sx;  sm.f.red[wave][1] = sy;  sm.f.red[wave][2] = sz;
    sm.f.red[wave][3] = mnx; sm.f.red[wave][4] = mny; sm.f.red[wave][5] = mnz;
    sm.f.red[wave][6] = mxx; sm.f.red[wave][7] = mxy; sm.f.red[wave][8] = mxz;
  }
  // zero histogram while waiting
  for (int i = t; i < NBUCK; i += NT) sm.f.hist[i] = 0;
  __syncthreads();
  if (t == 0) {
    float gx = 0.f, gy = 0.f, gz = 0.f;
    float a3 = sm.f.red[0][3], a4 = sm.f.red[0][4], a5 = sm.f.red[0][5];
    float a6 = sm.f.red[0][6], a7 = sm.f.red[0][7], a8 = sm.f.red[0][8];
    for (int w = 0; w < NWAVES; ++w) {
      gx += sm.f.red[w][0]; gy += sm.f.red[w][1]; gz += sm.f.red[w][2];
      a3 = fminf(a3, sm.f.red[w][3]); a4 = fminf(a4, sm.f.red[w][4]);
      a5 = fminf(a5, sm.f.red[w][5]);
      a6 = fmaxf(a6, sm.f.red[w][6]); a7 = fmaxf(a7, sm.f.red[w][7]);
      a8 = fmaxf(a8, sm.f.red[w][8]);
    }
    sm.f.st9[0] = gx / NN; sm.f.st9[1] = gy / NN; sm.f.st9[2] = gz / NN;
    sm.f.st9[3] = a3; sm.f.st9[4] = a4; sm.f.st9[5] = a5;
    sm.f.st9[6] = a6; sm.f.st9[7] = a7; sm.f.st9[8] = a8;
  }
  __syncthreads();
  const float ctx = sm.f.st9[0], cty = sm.f.st9[1], ctz = sm.f.st9[2];
  const float qmnx = sm.f.st9[3], qmny = sm.f.st9[4], qmnz = sm.f.st9[5];
  const float eps = 1e-30f;
  const float sclx = 15.9999f / fmaxf(sm.f.st9[6] - qmnx, eps);
  const float scly = 15.9999f / fmaxf(sm.f.st9[7] - qmny, eps);
  const float sclz = 15.9999f / fmaxf(sm.f.st9[8] - qmnz, eps);

  // ---- phase 1: morton codes + histogram ----
  int code[PPT];
#pragma unroll
  for (int k = 0; k < PPT; ++k) {
    int qx = (int)((rx[k] - qmnx) * sclx); qx = qx > 15 ? 15 : qx;
    int qy = (int)((ry[k] - qmny) * scly); qy = qy > 15 ? 15 : qy;
    int qz = (int)((rz[k] - qmnz) * sclz); qz = qz > 15 ? 15 : qz;
    code[k] = morton12(qx, qy, qz);
    atomicAdd(&sm.f.hist[code[k]], 1);
  }
  __syncthreads();

  // ---- phase 2: two-level exclusive scan of 4096 counts ----
  int loc[8]; int ssum = 0;
#pragma unroll
  for (int i = 0; i < 8; ++i) { loc[i] = ssum; ssum += sm.f.hist[t * 8 + i]; }
  int sc = ssum;
#pragma unroll
  for (int off = 1; off < 64; off <<= 1) {
    int o = __shfl_up(sc, off);
    if (lane >= off) sc += o;
  }
  if (lane == 63) sm.f.wsum[wave] = sc;
  __syncthreads();
  int woff = 0;
  for (int w = 0; w < wave; ++w) woff += sm.f.wsum[w];
  int tbase = woff + sc - ssum;
#pragma unroll
  for (int i = 0; i < 8; ++i) sm.f.hist[t * 8 + i] = tbase + loc[i];
  __syncthreads();

  // ---- phase 3: scatter into sorted order (atomic slot within bucket;
  // placement nondeterminism is benign: key-max is permutation-invariant) ----
#pragma unroll
  for (int k = 0; k < PPT; ++k) {
    int pos = atomicAdd(&sm.f.hist[code[k]], 1);
    sm.f.px[pos] = rx[k]; sm.f.py[pos] = ry[k]; sm.f.pz[pos] = rz[k];
    sm.f.pn[pos] = (unsigned short)(t + k * NT);
  }
  __syncthreads();

  // ---- phase 4: read back my cluster (16 consecutive sorted points) ----
  const int p0 = t * PPT;
  v2f px2[NPAIR], py2[NPAIR], pz2[NPAIR];
  v2u dist2[NPAIR];
  uu  low[PPT];
  float csx = 0.f, csy = 0.f, csz = 0.f;
#pragma unroll
  for (int k = 0; k < PPT; ++k) {
    float x = sm.f.px[p0 + k], y = sm.f.py[p0 + k], z = sm.f.pz[p0 + k];
    int n = (int)sm.f.pn[p0 + k];
    if (k & 1) { px2[k >> 1].y = x; py2[k >> 1].y = y; pz2[k >> 1].y = z; }
    else       { px2[k >> 1].x = x; py2[k >> 1].x = y * 0.f + x;  // keep simple
                 px2[k >> 1].x = x; py2[k >> 1].x = y; pz2[k >> 1].x = z; }
    low[k] = ~(uu)(((uu)n << 13) | (uu)(p0 + k));
    csx += x; csy += y; csz += z;
  }
  const float ictrx = csx * 0.0625f, ictry = csy * 0.0625f, ictrz = csz * 0.0625f;
  float r2m = 0.f;
#pragma unroll
  for (int k = 0; k < PPT; ++k) {
    float x = (k & 1) ? px2[k >> 1].y : px2[k >> 1].x;
    float y = (k & 1) ? py2[k >> 1].y : py2[k >> 1].x;
    float z = (k & 1) ? pz2[k >> 1].y : pz2[k >> 1].x;
    float ddx = x - ictrx, ddy = y - ictry, ddz = z - ictrz;
    r2m = fmaxf(r2m, fmaf(ddx, ddx, fmaf(ddy, ddy, ddz * ddz)));
  }
  const float rr = __fsqrt_rn(r2m) * 1.0001f + 1e-7f;   // conservative radius
  const uu INIT = __float_as_uint(1e10f);               // jnp.full(1e10)
#pragma unroll
  for (int j = 0; j < NPAIR; ++j) dist2[j] = (v2u){INIT, INIT};
  uu vcache = 0x7f800000u;    // +inf bits: force full path until first update
  uu lowcache = 0u;

  int ep = 0, cpos = 0, corig = 0;

  auto reduce_tail = [&](uu v, uu blow) {
    ull key = ((ull)v << 32) | blow;
    key = wave_max63(key);
    ep ^= 1;
    if (lane == 63) sm.f.key[ep][wave] = key;
    LDS_BARRIER();
    ull kk = sm.f.key[ep][lane & 7];   // spread ds_read_b64, conflict-free
    kk = dpp_max64<0xB1>(kk);
    kk = dpp_max64<0x4E>(kk);
    kk = dpp_max64<0x124>(kk);         // all lanes hold block max
    uu X = ~(uu)kk;
    cpos = (int)(X & 0x1FFFu);         // sorted position (coord fetch)
    corig = (int)(X >> 13);            // original index (output)
  };

  // ---- initial farthest = argmax of dist-to-centroid ----
  {
    v2f c2x = {ctx, ctx}, c2y = {cty, cty}, c2z = {ctz, ctz};
    v2u nd2[NPAIR];
    uu v = 0u;
#pragma unroll
    for (int j = 0; j < NPAIR; ++j) {
      v2f dx = pk_sub(px2[j], c2x);
      v2f dy = pk_sub(py2[j], c2y);
      v2f dz = pk_sub(pz2[j], c2z);
      v2f d = pk_add(pk_add(pk_mul(dx, dx), pk_mul(dy, dy)), pk_mul(dz, dz));
      v2u du = (v2u){__float_as_uint(d.x), __float_as_uint(d.y)};
      nd2[j] = du;
      v = umax2(v, umax2(du.x, du.y));
    }
    uu blow = 0u;
#pragma unroll
    for (int k = 0; k < PPT; ++k) {
      uu ndk = (k & 1) ? nd2[k >> 1].y : nd2[k >> 1].x;
      uu tmp = umax2(blow, low[k]);
      blow = (ndk == v) ? tmp : blow;   // max low among matches = min orig_n
    }
    reduce_tail(v, blow);
  }

  // ---- FPS main loop ----
  for (int m = 0; m < M; ++m) {
    float cx = sm.f.px[cpos], cy = sm.f.py[cpos], cz = sm.f.pz[cpos];
    if (t == 0) {
      idx_out[b * M + m] = corig;
      size_t o = ((size_t)b * M + m) * 3;
      out_pts[o] = cx; out_pts[o + 1] = cy; out_pts[o + 2] = cz;
    }
    if (m == M - 1) break;

    // Conservative cluster prune: if (|c-ctr|*0.9999 - rr)^2*0.9999 exceeds
    // the cluster's max dist, then d(n,c) > dist[n] for every point here ->
    // min() is the identity, cached (v, low) stay exact. Margins ~1e-4 dwarf
    // all f32 rounding (<=1e-6), so the skip is provably exact.
    float dxc = cx - ictrx, dyc = cy - ictry, dzc = cz - ictrz;
    float dc2 = fmaf(dxc, dxc, fmaf(dyc, dyc, dzc * dzc));
    float dcf = __fsqrt_rn(dc2);
    float lbf = dcf * 0.9999f - rr;
    float lb2 = lbf * lbf * 0.9999f;
    bool prune = (lbf > 0.f) && (__float_as_uint(lb2) > vcache);

    uu v, blow;
    if (__all(prune)) {
      v = vcache; blow = lowcache;       // whole wave skips: identity update
    } else {
      v2f c2x = {cx, cx}, c2y = {cy, cy}, c2z = {cz, cz};
      v2u nd2[NPAIR];
      v = 0u;
#pragma unroll
      for (int j = 0; j < NPAIR; ++j) {
        v2f dx = pk_sub(px2[j], c2x);
        v2f dy = pk_sub(py2[j], c2y);
        v2f dz = pk_sub(pz2[j], c2z);
        // exact numpy order: ((dx*dx + dy*dy) + dz*dz), no FMA
        v2f d = pk_add(pk_add(pk_mul(dx, dx), pk_mul(dy, dy)), pk_mul(dz, dz));
        v2u nd;
        nd.x = umin2(dist2[j].x, __float_as_uint(d.x));
        nd.y = umin2(dist2[j].y, __float_as_uint(d.y));
        dist2[j] = nd;
        nd2[j] = nd;
        v = umax2(v, umax2(nd.x, nd.y));
      }
      blow = 0u;
#pragma unroll
      for (int k = 0; k < PPT; ++k) {
        uu ndk = (k & 1) ? nd2[k >> 1].y : nd2[k >> 1].x;
        uu tmp = umax2(blow, low[k]);
        blow = (ndk == v) ? tmp : blow;
      }
      vcache = v; lowcache = blow;
    }
    reduce_tail(v, blow);
  }
}

// Gather from transposed features: fully coalesced float4 both sides.
__global__ __launch_bounds__(256)
void gather_t_kernel(const float* __restrict__ trans,
                     const int* __restrict__ idx,
                     float* __restrict__ out_f, int M) {
  int gm = blockIdx.x * 4 + (threadIdx.x >> 6);
  if (gm >= BB * M) return;
  int lane = threadIdx.x & 63;
  int b = gm / M;
  int n = idx[gm];
  float4 v = *(const float4*)(trans + ((size_t)b * NN + n) * CC + lane * 4);
  *(float4*)(out_f + (size_t)gm * CC + lane * 4) = v;
}

// Fallback gather (ws too small for transpose).
__global__ __launch_bounds__(CC)
void gather_kernel(const float* __restrict__ feats, const int* __restrict__ idx,
                   float* __restrict__ out_f, int M) {
  const int bm = blockIdx.x;
  const int b = bm / M;
  const int n = idx[bm];
  const int c = threadIdx.x;
  out_f[(size_t)bm * CC + c] = feats[((size_t)b * CC + c) * NN + n];
}

extern "C" void kernel_launch(void* const* d_in, const int* in_sizes, int n_in,
                              void* d_out, int out_size, void* d_ws, size_t ws_size,
                              hipStream_t stream) {
  const float* points = (const float*)d_in[0];   // [B,3,N] f32
  const float* feats  = (const float*)d_in[1];   // [B,C,N] f32
  int M = out_size / (BB * (3 + CC));            // = 2048
  if (M <= 0) M = 1;

  float* out_pts = (float*)d_out;                        // [B,M,3]
  float* out_f   = (float*)d_out + (size_t)BB * M * 3;   // [B,M,C]

  int* idx_ws = (int*)d_ws;                              // B*M ints
  size_t idx_bytes = (((size_t)BB * M * sizeof(int)) + 255) & ~(size_t)255;
  size_t trans_bytes = (size_t)BB * NN * CC * sizeof(float);   // 134.2 MB
  bool use_t = (ws_size >= idx_bytes + trans_bytes);
  float* trans = (float*)((char*)d_ws + idx_bytes);

  int grid = use_t ? (BB + TBLOCKS) : BB;
  fps_fused_kernel<<<dim3(grid), dim3(NT), 0, stream>>>(
      points, feats, out_pts, idx_ws, trans, M, use_t ? 1 : 0);

  if (use_t) {
    gather_t_kernel<<<dim3((BB * M + 3) / 4), dim3(256), 0, stream>>>(
        trans, idx_ws, out_f, M);
  } else {
    gather_kernel<<<dim3(BB * M), dim3(CC), 0, stream>>>(feats, idx_ws, out_f, M);
  }
}